// Round 6
// baseline (180.665 us; speedup 1.0000x reference)
//
#include <hip/hip_runtime.h>

#define BATCH 8192
#define NV 128
#define NE 127
#define NCHUNK 31   // chunks of 4 edges: 0..30 cover edges 0..123; 124..126 remainder

typedef float v2f __attribute__((ext_vector_type(2)));

// Per-chunk register buffer, all float2-vectorized. ms1/sc1 rows start at an
// odd dword index, so they're staged through a -1-dword shifted window (start
// even => 8B aligned; reads land in the preceding row's last dword, in-bounds).
struct Buf {
  v2f ms0[18];   // ms0 row dwords [36c .. 36c+35]
  v2f ms1w[19];  // ms1 row dwords [36c-1 .. 36c+36]; edge float j = window dword j+1
  v2f vw[7];     // vin dwords [12c+2 .. 12c+15]; q float j = window dword j+1
  v2f s0v[2];    // sc0 row dwords [4c .. 4c+3]
  v2f s1w[3];    // sc1 row dwords [4c-1 .. 4c+4]; edge k = window dword k+1
  float nl[4];
  float zm[4];
};

#define MS0(k,j) (B.ms0[(9*(k)+(j))>>1][(9*(k)+(j))&1])
#define MS1(k,j) (B.ms1w[(9*(k)+(j)+1)>>1][(9*(k)+(j)+1)&1])
#define VV(j)    (B.vw[((j)+1)>>1][((j)+1)&1])
#define S0k(k)   (B.s0v[(k)>>1][(k)&1])
#define S1k(k)   (B.s1w[((k)+1)>>1][((k)+1)&1])

__device__ __forceinline__ void load_chunk(Buf& B, int c,
    const float* __restrict__ vin, const float* __restrict__ nl,
    const float* __restrict__ zm, const float* __restrict__ sc0,
    const float* __restrict__ sc1m1, const float* __restrict__ ms0,
    const float* __restrict__ ms1m1) {
  const v2f* __restrict__ pm0 = (const v2f*)(ms0 + 36 * c);
  const v2f* __restrict__ pm1 = (const v2f*)(ms1m1 + 36 * c);
  const v2f* __restrict__ pv  = (const v2f*)(vin + 12 * c + 2);
  const v2f* __restrict__ ps0 = (const v2f*)(sc0 + 4 * c);
  const v2f* __restrict__ ps1 = (const v2f*)(sc1m1 + 4 * c);
#pragma unroll
  for (int i = 0; i < 18; ++i) B.ms0[i] = pm0[i];
#pragma unroll
  for (int i = 0; i < 19; ++i) B.ms1w[i] = pm1[i];
#pragma unroll
  for (int i = 0; i < 7; ++i) B.vw[i] = pv[i];
  B.s0v[0] = ps0[0]; B.s0v[1] = ps0[1];
  B.s1w[0] = ps1[0]; B.s1w[1] = ps1[1]; B.s1w[2] = ps1[2];
#pragma unroll
  for (int i = 0; i < 4; ++i) { B.nl[i] = nl[4 * c + i]; B.zm[i] = zm[4 * c + i]; }
}

__device__ __forceinline__ void compute_chunk(const Buf& B, int c,
    float& px, float& py, float& pz, float* __restrict__ vout) {
  float out[12];
#pragma unroll
  for (int k = 0; k < 4; ++k) {
    float qx = VV(3 * k + 0), qy = VV(3 * k + 1), qz = VV(3 * k + 2);
    float zmv = B.zm[k];
    float ex = (qx - px) * zmv;
    float ey = (qy - py) * zmv;
    float ez = (qz - pz) * zmv;
    float nlv = B.nl[k];
    float nlsq = nlv * nlv;
    float denom = nlsq + (ex * ex + ey * ey + ez * ez);
    float l = 1.0f - 2.0f * nlsq * __builtin_amdgcn_rcpf(denom);
    float f0 = l * __builtin_amdgcn_rcpf(S0k(k));
    float f1 = l * __builtin_amdgcn_rcpf(S1k(k));
    float u0x = (MS0(k,0) * ex + MS0(k,1) * ey + MS0(k,2) * ez) * f0;
    float u0y = (MS0(k,3) * ex + MS0(k,4) * ey + MS0(k,5) * ez) * f0;
    float u0z = (MS0(k,6) * ex + MS0(k,7) * ey + MS0(k,8) * ez) * f0;
    float u1x = (MS1(k,0) * ex + MS1(k,1) * ey + MS1(k,2) * ez) * f1;
    float u1y = (MS1(k,3) * ex + MS1(k,4) * ey + MS1(k,5) * ez) * f1;
    float u1z = (MS1(k,6) * ex + MS1(k,7) * ey + MS1(k,8) * ez) * f1;
    out[3 * k + 0] = px + u0x;
    out[3 * k + 1] = py + u0y;
    out[3 * k + 2] = pz + u0z;
    px = qx + u1x;
    py = qy + u1y;
    pz = qz + u1z;
  }
  v2f* __restrict__ po = (v2f*)(vout + 12 * c);
#pragma unroll
  for (int i = 0; i < 6; ++i) { v2f t; t.x = out[2*i]; t.y = out[2*i+1]; po[i] = t; }
}

__global__ __launch_bounds__(8, 1) void rod_kernel(
    const float* __restrict__ vin_g,
    const float* __restrict__ nl_g,
    const float* __restrict__ sc_g,
    const float* __restrict__ ms_g,
    const float* __restrict__ zm_g,
    float* __restrict__ vout_g) {
  int b = blockIdx.x * blockDim.x + threadIdx.x;
  if (b >= BATCH) return;

  const float* __restrict__ vin  = vin_g  + (size_t)b * (NV * 3);
  float* __restrict__       vout = vout_g + (size_t)b * (NV * 3);
  const float* __restrict__ nl  = nl_g + (size_t)b * NE;
  const float* __restrict__ zm  = zm_g + (size_t)b * NE;
  const float* __restrict__ sc0 = sc_g + (size_t)(2 * b) * NE;
  const float* __restrict__ sc1m1 = sc0 + NE - 1;           // sc1 row shifted -1 (even dword)
  const float* __restrict__ ms0 = ms_g + (size_t)(2 * b) * NE * 9;
  const float* __restrict__ ms1m1 = ms0 + (size_t)NE * 9 - 1; // ms1 row shifted -1 (even dword)

  float px = vin[0], py = vin[1], pz = vin[2];

  Buf B0, B1, B2;
  load_chunk(B0, 0, vin, nl, zm, sc0, sc1m1, ms0, ms1m1);
  load_chunk(B1, 1, vin, nl, zm, sc0, sc1m1, ms0, ms1m1);
  load_chunk(B2, 2, vin, nl, zm, sc0, sc1m1, ms0, ms1m1);

  int c = 0;
  // 10 rotations of 3 chunks: computes chunks 0..29, prefetches up to chunk 30
  for (int t = 0; t < 10; ++t, c += 3) {
    compute_chunk(B0, c + 0, px, py, pz, vout);
    if (c + 3 < NCHUNK) load_chunk(B0, c + 3, vin, nl, zm, sc0, sc1m1, ms0, ms1m1);
    compute_chunk(B1, c + 1, px, py, pz, vout);
    if (c + 4 < NCHUNK) load_chunk(B1, c + 4, vin, nl, zm, sc0, sc1m1, ms0, ms1m1);
    compute_chunk(B2, c + 2, px, py, pz, vout);
    if (c + 5 < NCHUNK) load_chunk(B2, c + 5, vin, nl, zm, sc0, sc1m1, ms0, ms1m1);
  }
  // chunk 30 (edges 120..123) is in B0
  compute_chunk(B0, 30, px, py, pz, vout);

  // remainder edges 124..126, scalar
  for (int e = 124; e < NE; ++e) {
    float qx = vin[3 * e + 3];
    float qy = vin[3 * e + 4];
    float qz = vin[3 * e + 5];
    float zmv = zm[e];
    float ex = (qx - px) * zmv;
    float ey = (qy - py) * zmv;
    float ez = (qz - pz) * zmv;
    float nlv = nl[e];
    float nlsq = nlv * nlv;
    float denom = nlsq + (ex * ex + ey * ey + ez * ez);
    float l = 1.0f - 2.0f * nlsq * __builtin_amdgcn_rcpf(denom);
    float f0 = l * __builtin_amdgcn_rcpf(sc0[e]);
    float f1 = l * __builtin_amdgcn_rcpf(*(sc1m1 + 1 + e));
    const float* m0 = ms0 + 9 * e;
    const float* m1 = ms1m1 + 1 + 9 * e;
    float u0x = (m0[0] * ex + m0[1] * ey + m0[2] * ez) * f0;
    float u0y = (m0[3] * ex + m0[4] * ey + m0[5] * ez) * f0;
    float u0z = (m0[6] * ex + m0[7] * ey + m0[8] * ez) * f0;
    float u1x = (m1[0] * ex + m1[1] * ey + m1[2] * ez) * f1;
    float u1y = (m1[3] * ex + m1[4] * ey + m1[5] * ez) * f1;
    float u1z = (m1[6] * ex + m1[7] * ey + m1[8] * ez) * f1;
    vout[3 * e + 0] = px + u0x;
    vout[3 * e + 1] = py + u0y;
    vout[3 * e + 2] = pz + u0z;
    px = qx + u1x;
    py = qy + u1y;
    pz = qz + u1z;
  }
  vout[3 * NE + 0] = px;
  vout[3 * NE + 1] = py;
  vout[3 * NE + 2] = pz;
}

extern "C" void kernel_launch(void* const* d_in, const int* in_sizes, int n_in,
                              void* d_out, int out_size, void* d_ws, size_t ws_size,
                              hipStream_t stream) {
  const float* vin = (const float*)d_in[0];   // current_vertices (B,N,3)
  const float* nl  = (const float*)d_in[1];   // nominal_length   (B,N-1)
  const float* sc  = (const float*)d_in[2];   // scale            (2B,N-1)
  const float* ms  = (const float*)d_in[3];   // mass_scale       (2B,N-1,3,3)
  const float* zm  = (const float*)d_in[4];   // zero_mask_num    (B,N-1)
  float* vout = (float*)d_out;                // (B,N,3)

  // 1024 blocks x 8 threads: 4 independent waves per CU overlap their
  // load-issue/latency pipelines; lanes are free (VALUBusy ~5%).
  dim3 grid(BATCH / 8);
  dim3 block(8);
  hipLaunchKernelGGL(rod_kernel, grid, block, 0, stream, vin, nl, sc, ms, zm, vout);
}

// Round 7
// 159.568 us; speedup vs baseline: 1.1322x; 1.1322x over previous
//
#include <hip/hip_runtime.h>

#define BATCH 8192
#define NV 128
#define NE 127
#define NCHUNK 31   // chunks of 4 edges: 0..30 cover edges 0..123; 124..126 tail

typedef float v2f __attribute__((ext_vector_type(2)));

// Two lanes per rod: even lane owns endpoint-0 rows (ms0/sc0), odd lane owns
// endpoint-1 rows (ms1/sc1). Odd rows start at odd dword indices, so the odd
// lane's base is shifted -1 dword (making it even => 8B-aligned v2f loads) and
// element i sits at window position i+1; selected via compile-time-indexed
// `odd ? W[i+1] : W[i]` (one v_cndmask per use, static register indexing).
struct Buf {
  v2f m[19];    // own ms row window: even [36c..36c+37], odd [36c-1..36c+36]+base
  v2f vw[7];    // vin dwords [12c+2..12c+15] (shared by the pair); q float j at j+1
  v2f scw[3];   // own sc row window: even k@k, odd k@k+1
  float nl[4];
  float zm[4];
};

#define MW(BB,i)  ((BB).m[(i)>>1][(i)&1])
#define VVW(BB,j) ((BB).vw[((j)+1)>>1][((j)+1)&1])
#define SCW(BB,i) ((BB).scw[(i)>>1][(i)&1])

__device__ __forceinline__ void load_chunk(Buf& B, int c,
    const float* __restrict__ mbase, const float* __restrict__ scbase,
    const float* __restrict__ vin, const float* __restrict__ nl,
    const float* __restrict__ zm) {
  const v2f* __restrict__ pm = (const v2f*)(mbase + 36 * c);
#pragma unroll
  for (int i = 0; i < 19; ++i) B.m[i] = pm[i];
  const v2f* __restrict__ pv = (const v2f*)(vin + 12 * c + 2);
#pragma unroll
  for (int i = 0; i < 7; ++i) B.vw[i] = pv[i];
  const v2f* __restrict__ ps = (const v2f*)(scbase + 4 * c);
#pragma unroll
  for (int i = 0; i < 3; ++i) B.scw[i] = ps[i];
#pragma unroll
  for (int i = 0; i < 4; ++i) { B.nl[i] = nl[4 * c + i]; B.zm[i] = zm[4 * c + i]; }
}

__device__ __forceinline__ void compute_chunk(const Buf& B, int c, bool odd, int up,
    float& px, float& py, float& pz, float* __restrict__ vout) {
  float out[12];
#pragma unroll
  for (int k = 0; k < 4; ++k) {
    float qx = VVW(B, 3 * k + 0), qy = VVW(B, 3 * k + 1), qz = VVW(B, 3 * k + 2);
    float zmv = B.zm[k], nlv = B.nl[k];
    float ex = (qx - px) * zmv;
    float ey = (qy - py) * zmv;
    float ez = (qz - pz) * zmv;
    float nlsq = nlv * nlv;
    float denom = nlsq + (ex * ex + ey * ey + ez * ez);
    float l = 1.0f - 2.0f * nlsq * __builtin_amdgcn_rcpf(denom);
    float scv = odd ? SCW(B, k + 1) : SCW(B, k);
    float f = l * __builtin_amdgcn_rcpf(scv);
    float m0 = odd ? MW(B, 9*k+1) : MW(B, 9*k+0);
    float m1 = odd ? MW(B, 9*k+2) : MW(B, 9*k+1);
    float m2 = odd ? MW(B, 9*k+3) : MW(B, 9*k+2);
    float m3 = odd ? MW(B, 9*k+4) : MW(B, 9*k+3);
    float m4 = odd ? MW(B, 9*k+5) : MW(B, 9*k+4);
    float m5 = odd ? MW(B, 9*k+6) : MW(B, 9*k+5);
    float m6 = odd ? MW(B, 9*k+7) : MW(B, 9*k+6);
    float m7 = odd ? MW(B, 9*k+8) : MW(B, 9*k+7);
    float m8 = odd ? MW(B, 9*k+9) : MW(B, 9*k+8);
    float ux = (m0 * ex + m1 * ey + m2 * ez) * f;  // even: u0, odd: u1
    float uy = (m3 * ex + m4 * ey + m5 * ez) * f;
    float uz = (m6 * ex + m7 * ey + m8 * ez) * f;
    out[3 * k + 0] = px + ux;   // meaningful on even lane (stored vertex)
    out[3 * k + 1] = py + uy;
    out[3 * k + 2] = pz + uz;
    float nx_ = qx + ux, ny_ = qy + uy, nz_ = qz + uz;  // odd lane: new carry
    px = __shfl(nx_, up);   // broadcast odd lane's p_new to the pair
    py = __shfl(ny_, up);
    pz = __shfl(nz_, up);
  }
  if (!odd) {
    v2f* __restrict__ po = (v2f*)(vout + 12 * c);
#pragma unroll
    for (int i = 0; i < 6; ++i) { v2f t; t[0] = out[2*i]; t[1] = out[2*i+1]; po[i] = t; }
  }
}

__global__ __launch_bounds__(64, 1) void rod_kernel(
    const float* __restrict__ vin_g,
    const float* __restrict__ nl_g,
    const float* __restrict__ sc_g,
    const float* __restrict__ ms_g,
    const float* __restrict__ zm_g,
    float* __restrict__ vout_g) {
  int tid = threadIdx.x;
  bool odd = (tid & 1) != 0;
  int up = tid | 1;                       // odd lane of this pair
  int b = blockIdx.x * 32 + (tid >> 1);   // rod index

  const float* __restrict__ vin  = vin_g  + (size_t)b * (NV * 3);
  float* __restrict__       vout = vout_g + (size_t)b * (NV * 3);
  const float* __restrict__ nl   = nl_g + (size_t)b * NE;
  const float* __restrict__ zm   = zm_g + (size_t)b * NE;
  const float* __restrict__ scbase = sc_g + (size_t)(2 * b) * NE + (odd ? NE - 1 : 0);
  const float* __restrict__ mbase  = ms_g + (size_t)(2 * b) * NE * 9 + (odd ? (size_t)NE * 9 - 1 : 0);

  float px = vin[0], py = vin[1], pz = vin[2];

  Buf B0, B1, B2;
  load_chunk(B0, 0, mbase, scbase, vin, nl, zm);
  load_chunk(B1, 1, mbase, scbase, vin, nl, zm);
  load_chunk(B2, 2, mbase, scbase, vin, nl, zm);

  int c = 0;
  for (int t = 0; t < 10; ++t, c += 3) {
    compute_chunk(B0, c + 0, odd, up, px, py, pz, vout);
    if (c + 3 < NCHUNK) load_chunk(B0, c + 3, mbase, scbase, vin, nl, zm);
    compute_chunk(B1, c + 1, odd, up, px, py, pz, vout);
    if (c + 4 < NCHUNK) load_chunk(B1, c + 4, mbase, scbase, vin, nl, zm);
    compute_chunk(B2, c + 2, odd, up, px, py, pz, vout);
    if (c + 5 < NCHUNK) load_chunk(B2, c + 5, mbase, scbase, vin, nl, zm);
  }
  compute_chunk(B0, 30, odd, up, px, py, pz, vout);

  // tail edges 124..126, scalar; same pair-split via +odd offsets
#pragma unroll
  for (int e = 124; e < NE; ++e) {
    float qx = vin[3 * e + 3], qy = vin[3 * e + 4], qz = vin[3 * e + 5];
    float zmv = zm[e], nlv = nl[e];
    float ex = (qx - px) * zmv;
    float ey = (qy - py) * zmv;
    float ez = (qz - pz) * zmv;
    float nlsq = nlv * nlv;
    float denom = nlsq + (ex * ex + ey * ey + ez * ez);
    float l = 1.0f - 2.0f * nlsq * __builtin_amdgcn_rcpf(denom);
    float f = l * __builtin_amdgcn_rcpf(scbase[e + (odd ? 1 : 0)]);
    const float* mr = mbase + 9 * e + (odd ? 1 : 0);   // = own ms row + 9e
    float ux = (mr[0] * ex + mr[1] * ey + mr[2] * ez) * f;
    float uy = (mr[3] * ex + mr[4] * ey + mr[5] * ez) * f;
    float uz = (mr[6] * ex + mr[7] * ey + mr[8] * ez) * f;
    if (!odd) {
      vout[3 * e + 0] = px + ux;
      vout[3 * e + 1] = py + uy;
      vout[3 * e + 2] = pz + uz;
    }
    float nx_ = qx + ux, ny_ = qy + uy, nz_ = qz + uz;
    px = __shfl(nx_, up);
    py = __shfl(ny_, up);
    pz = __shfl(nz_, up);
  }
  if (!odd) {
    vout[3 * NE + 0] = px;
    vout[3 * NE + 1] = py;
    vout[3 * NE + 2] = pz;
  }
}

extern "C" void kernel_launch(void* const* d_in, const int* in_sizes, int n_in,
                              void* d_out, int out_size, void* d_ws, size_t ws_size,
                              hipStream_t stream) {
  const float* vin = (const float*)d_in[0];   // current_vertices (B,N,3)
  const float* nl  = (const float*)d_in[1];   // nominal_length   (B,N-1)
  const float* sc  = (const float*)d_in[2];   // scale            (2B,N-1)
  const float* ms  = (const float*)d_in[3];   // mass_scale       (2B,N-1,3,3)
  const float* zm  = (const float*)d_in[4];   // zero_mask_num    (B,N-1)
  float* vout = (float*)d_out;                // (B,N,3)

  // 2 lanes per rod: 256 blocks x 64 threads = one FULL wave per CU.
  // Cuts per-CU VMEM instruction count ~3x vs R4 (the fitted a-term).
  dim3 grid(BATCH / 32);
  dim3 block(64);
  hipLaunchKernelGGL(rod_kernel, grid, block, 0, stream, vin, nl, sc, ms, zm, vout);
}

// Round 8
// 158.687 us; speedup vs baseline: 1.1385x; 1.0056x over previous
//
#include <hip/hip_runtime.h>

#define BATCH 8192
#define NV 128
#define NE 127
#define NCHUNK 31   // chunks of 4 edges: 0..30 cover edges 0..123; 124..126 tail

// 4B-aligned float4: gfx9+ global loads/stores support dword alignment, so
// clang emits global_load_dwordx4 at arbitrary dword offsets (no shifted
// windows or cross-lane selects needed). If the backend ever splits these,
// we degenerate to the R7 dwordx2 cost — no regression.
typedef float v4fu __attribute__((ext_vector_type(4), aligned(4)));

// Two lanes per rod: even lane owns endpoint-0 rows (ms0/sc0), odd lane owns
// endpoint-1 rows (ms1/sc1), each at its EXACT row offset.
struct Buf {
  v4fu m[9];    // own ms row dwords [36c .. 36c+36)
  v4fu vw[3];   // vin dwords [12c+3 .. 12c+15)  (q vertices of the 4 edges)
  v4fu sc;      // own sc row dwords [4c .. 4c+4)
  v4fu nl;      // nl [4c .. 4c+4)
  v4fu zm;      // zm [4c .. 4c+4)
};

#define MW(k,j) (B.m[(9*(k)+(j))>>2][(9*(k)+(j))&3])
#define VVW(j)  (B.vw[(j)>>2][(j)&3])

__device__ __forceinline__ void load_chunk(Buf& B, int c,
    const float* mbase, const float* scbase,
    const float* vin, const float* nl, const float* zm) {
  const v4fu* pm = (const v4fu*)(mbase + 36 * c);
#pragma unroll
  for (int i = 0; i < 9; ++i) B.m[i] = pm[i];
  const v4fu* pv = (const v4fu*)(vin + 12 * c + 3);
#pragma unroll
  for (int i = 0; i < 3; ++i) B.vw[i] = pv[i];
  B.sc = *(const v4fu*)(scbase + 4 * c);
  B.nl = *(const v4fu*)(nl + 4 * c);
  B.zm = *(const v4fu*)(zm + 4 * c);
}

__device__ __forceinline__ void compute_chunk(const Buf& B, int c, bool odd, int up,
    float& px, float& py, float& pz, float* vout) {
  float out[12];
#pragma unroll
  for (int k = 0; k < 4; ++k) {
    float qx = VVW(3 * k + 0), qy = VVW(3 * k + 1), qz = VVW(3 * k + 2);
    float zmv = B.zm[k], nlv = B.nl[k];
    float ex = (qx - px) * zmv;
    float ey = (qy - py) * zmv;
    float ez = (qz - pz) * zmv;
    float nlsq = nlv * nlv;
    float denom = nlsq + (ex * ex + ey * ey + ez * ez);
    float l = 1.0f - 2.0f * nlsq * __builtin_amdgcn_rcpf(denom);
    float f = l * __builtin_amdgcn_rcpf(B.sc[k]);
    float ux = (MW(k,0) * ex + MW(k,1) * ey + MW(k,2) * ez) * f;  // even: u0, odd: u1
    float uy = (MW(k,3) * ex + MW(k,4) * ey + MW(k,5) * ez) * f;
    float uz = (MW(k,6) * ex + MW(k,7) * ey + MW(k,8) * ez) * f;
    out[3 * k + 0] = px + ux;   // meaningful on even lane (stored vertex)
    out[3 * k + 1] = py + uy;
    out[3 * k + 2] = pz + uz;
    float nx_ = qx + ux, ny_ = qy + uy, nz_ = qz + uz;  // odd lane: new carry
    px = __shfl(nx_, up);   // broadcast odd lane's p_new to the pair
    py = __shfl(ny_, up);
    pz = __shfl(nz_, up);
  }
  if (!odd) {
    v4fu* po = (v4fu*)(vout + 12 * c);
#pragma unroll
    for (int i = 0; i < 3; ++i) {
      v4fu t;
      t[0] = out[4*i+0]; t[1] = out[4*i+1]; t[2] = out[4*i+2]; t[3] = out[4*i+3];
      po[i] = t;
    }
  }
}

__global__ __launch_bounds__(64, 1) void rod_kernel(
    const float* __restrict__ vin_g,
    const float* __restrict__ nl_g,
    const float* __restrict__ sc_g,
    const float* __restrict__ ms_g,
    const float* __restrict__ zm_g,
    float* __restrict__ vout_g) {
  int tid = threadIdx.x;
  bool odd = (tid & 1) != 0;
  int up = tid | 1;                       // odd lane of this pair
  int b = blockIdx.x * 32 + (tid >> 1);   // rod index

  const float* vin  = vin_g  + (size_t)b * (NV * 3);
  float*       vout = vout_g + (size_t)b * (NV * 3);
  const float* nl   = nl_g + (size_t)b * NE;
  const float* zm   = zm_g + (size_t)b * NE;
  const float* scbase = sc_g + (size_t)(2 * b + (odd ? 1 : 0)) * NE;
  const float* mbase  = ms_g + (size_t)(2 * b + (odd ? 1 : 0)) * NE * 9;

  float px = vin[0], py = vin[1], pz = vin[2];

  Buf B0, B1, B2;
  load_chunk(B0, 0, mbase, scbase, vin, nl, zm);
  load_chunk(B1, 1, mbase, scbase, vin, nl, zm);
  load_chunk(B2, 2, mbase, scbase, vin, nl, zm);
  __builtin_amdgcn_sched_barrier(0);

  int c = 0;
  for (int t = 0; t < 10; ++t, c += 3) {
    compute_chunk(B0, c + 0, odd, up, px, py, pz, vout);
    if (c + 3 < NCHUNK) load_chunk(B0, c + 3, mbase, scbase, vin, nl, zm);
    __builtin_amdgcn_sched_barrier(0);   // pin: prefetch issues before next compute
    compute_chunk(B1, c + 1, odd, up, px, py, pz, vout);
    if (c + 4 < NCHUNK) load_chunk(B1, c + 4, mbase, scbase, vin, nl, zm);
    __builtin_amdgcn_sched_barrier(0);
    compute_chunk(B2, c + 2, odd, up, px, py, pz, vout);
    if (c + 5 < NCHUNK) load_chunk(B2, c + 5, mbase, scbase, vin, nl, zm);
    __builtin_amdgcn_sched_barrier(0);
  }
  compute_chunk(B0, 30, odd, up, px, py, pz, vout);

  // tail edges 124..126, scalar; exact per-lane row bases
#pragma unroll
  for (int e = 124; e < NE; ++e) {
    float qx = vin[3 * e + 3], qy = vin[3 * e + 4], qz = vin[3 * e + 5];
    float zmv = zm[e], nlv = nl[e];
    float ex = (qx - px) * zmv;
    float ey = (qy - py) * zmv;
    float ez = (qz - pz) * zmv;
    float nlsq = nlv * nlv;
    float denom = nlsq + (ex * ex + ey * ey + ez * ez);
    float l = 1.0f - 2.0f * nlsq * __builtin_amdgcn_rcpf(denom);
    float f = l * __builtin_amdgcn_rcpf(scbase[e]);
    const float* mr = mbase + 9 * e;
    float ux = (mr[0] * ex + mr[1] * ey + mr[2] * ez) * f;
    float uy = (mr[3] * ex + mr[4] * ey + mr[5] * ez) * f;
    float uz = (mr[6] * ex + mr[7] * ey + mr[8] * ez) * f;
    if (!odd) {
      vout[3 * e + 0] = px + ux;
      vout[3 * e + 1] = py + uy;
      vout[3 * e + 2] = pz + uz;
    }
    float nx_ = qx + ux, ny_ = qy + uy, nz_ = qz + uz;
    px = __shfl(nx_, up);
    py = __shfl(ny_, up);
    pz = __shfl(nz_, up);
  }
  if (!odd) {
    vout[3 * NE + 0] = px;
    vout[3 * NE + 1] = py;
    vout[3 * NE + 2] = pz;
  }
}

extern "C" void kernel_launch(void* const* d_in, const int* in_sizes, int n_in,
                              void* d_out, int out_size, void* d_ws, size_t ws_size,
                              hipStream_t stream) {
  const float* vin = (const float*)d_in[0];   // current_vertices (B,N,3)
  const float* nl  = (const float*)d_in[1];   // nominal_length   (B,N-1)
  const float* sc  = (const float*)d_in[2];   // scale            (2B,N-1)
  const float* ms  = (const float*)d_in[3];   // mass_scale       (2B,N-1,3,3)
  const float* zm  = (const float*)d_in[4];   // zero_mask_num    (B,N-1)
  float* vout = (float*)d_out;                // (B,N,3)

  // 2 lanes per rod: 256 blocks x 64 threads = one full wave per CU.
  // dwordx4 loads cut per-CU lane-address traffic ~2.2x vs R7.
  dim3 grid(BATCH / 32);
  dim3 block(64);
  hipLaunchKernelGGL(rod_kernel, grid, block, 0, stream, vin, nl, sc, ms, zm, vout);
}